// Round 11
// baseline (227.884 us; speedup 1.0000x reference)
//
#include <hip/hip_runtime.h>

#define B_DIM 4096
#define L_DIM 4096
#define SEGLEN 256
#define NSEG (L_DIM / SEGLEN)   // 16
#define WARM 512                // coupling window (proven exact)
#define CHUNK 128               // time steps per chunk -> 512B per row-visit
#define LROW 128                // LDS floats per row (linear, gll dest)

typedef __attribute__((ext_vector_type(4))) float f32x4;  // native vec for nt-store

// Exact IEEE step (proven absmax 0): q = RN(u/20) via Markstein, compare off
// the dependent chain: u' = sp_prev ? I' : ((u - q) + I')
#define LIF_CORE(IIN)                         \
    float q0 = u * cdiv;                      \
    float rr = fmaf(-20.0f, q0, u);           \
    float q  = fmaf(rr, cdiv, q0);            \
    float a  = u - q;                         \
    float b  = a + (IIN);                     \
    u = sp ? (IIN) : b;                       \
    sp = (u >= 1.0f);

#define WARM_STEP(IIN) { LIF_CORE(IIN) }

#define FULL_STEP(IIN, SOUT)                  \
    {                                         \
        LIF_CORE(IIN)                         \
        float sf = sp ? 1.0f : 0.0f;          \
        cnt += sf;                            \
        seen = fmaxf(seen, sf);               \
        accS += cnt;                          \
        accF += seen;                         \
        (SOUT) = sf;                          \
    }

typedef const __attribute__((address_space(1))) void g_void;
typedef __attribute__((address_space(3))) void l_void;
__device__ __forceinline__ void gll16(const float* src, float* ldsbase) {
    // async global->LDS, 16B/lane; LDS dest = wave-uniform base + lane*16B
    __builtin_amdgcn_global_load_lds((g_void*)src, (l_void*)ldsbase, 16, 0, 0);
}

// ROUND 11 = round-10 resubmission (infra failure, no data). R9 machinery
// verbatim, re-parameterized CHUNK 64 -> 128.
//
// Evidence: dispatch-109 (R9) had FETCH~0 (input L3-resident) yet identical
// dur -> NOT HBM-bound; the demand path (L3/L2->CU) caps at ~3.4 TB/s for
// 256B-per-row visits. Granularity scaling measured: 128B->2.75, 256B->3.4
// TB/s. This round: 512B visits (32 back-to-back 1KB gll per chunk).
//
// Geometry: LDS 2 waves x 2 bufs x 32KB = 128KB/block -> 1 block/CU
// (gfx950 LDS/CU = 160KB; >64KB static LDS already proven in round 4).
// 512 waves x 2 sequential segments (segA in 0..7, then segA+8) = all 1024
// segment-tasks resident in ONE round (256 blocks).
// Everything else proven: fully decoupled waves, zero barriers; gll linear
// LDS dest + both-sides swizzle (block (k-r)&31 / slot (j+lane)&31, same
// bank math as R9's &15 which measured 0 conflicts); depth-1 prefetch;
// counted vmcnt(32) retains this iter's 32 nt-stores, drains the 32 gll;
// spikes overwrite the just-consumed buffer (same-wave in-order LDS);
// S-extraction in two 16-reg batches (VGPR peak bounded, no spill --
// WRITE_SIZE is the spill canary).
static_assert(2 * 2 * 64 * LROW * sizeof(float) == 131072, "LDS geometry");

__global__ __launch_bounds__(128, 1) void lif_kernel(const float* __restrict__ I,
                                                     float* __restrict__ out,
                                                     float* __restrict__ Cacc,
                                                     float* __restrict__ tsAcc,
                                                     int* __restrict__ firstAcc) {
    __shared__ __align__(16) float lds[2][2][64 * LROW];  // 128 KB
    const int wid = threadIdx.x >> 6;
    const int lane = threadIdx.x & 63;
    float* buf0 = &lds[wid][0][0];
    float* buf1 = &lds[wid][1][0];

    // 256 blocks: rowgroup = b&63, pair = b>>6 (0..3); wave does segA, segA+8
    const int rowBase = (blockIdx.x & 63) * 64;
    const int segA = ((blockIdx.x >> 6) << 1) + wid;   // 0..7

    const int srow = lane >> 5, scol = lane & 31;      // 2 rows x 512B per gll
    const int row = rowBase + lane;
    const float* Ibase = I + (size_t)rowBase * L_DIM;
    const float cdiv = 0.05f;  // RN(1/20)

#define GLL_CHUNK(GB, CC, DST)                                              \
    {                                                                       \
        const float* gsrc = (GB) + (size_t)(CC) * CHUNK;                    \
        _Pragma("unroll")                                                   \
        for (int p = 0; p < 32; ++p) {                                      \
            const int r = 2 * p + srow;                                     \
            gll16(gsrc + (size_t)r * L_DIM + (((scol - r) & 31) << 2),      \
                  (DST) + p * 256);                                         \
        }                                                                   \
    }

#define READ_R(SRC)                                                         \
    {                                                                       \
        _Pragma("unroll")                                                   \
        for (int j = 0; j < 32; ++j)                                        \
            R[j] = *(const float4*)&(SRC)[lane * LROW + (((j + lane) & 31) << 2)]; \
    }

    for (int task = 0; task < 2; ++task) {
        const int seg = segA + 8 * task;
        const int t0 = seg * SEGLEN;
        const int start = (t0 > WARM) ? (t0 - WARM) : 0;
        const int nwarmCh = (t0 - start) / CHUNK;   // 0..4
        const int nch = nwarmCh + SEGLEN / CHUNK;   // 2..6
        const float* gbase = Ibase + start;

        float u = 0.f, cnt = 0.f, seen = 0.f, accS = 0.f, accF = 0.f;
        bool sp = false;
        float4 R[32];

        // prologue: chunk 0 -> LDS -> R (drains any previous-task stores too)
        GLL_CHUNK(gbase, 0, buf0)
        asm volatile("s_waitcnt vmcnt(0)" ::: "memory");
        __builtin_amdgcn_sched_barrier(0);
        READ_R(buf0)

        for (int c = 0; c < nch; ++c) {
            float* bufc = (c & 1) ? buf1 : buf0;
            float* bufn = (c & 1) ? buf0 : buf1;

            // 1. async-stage chunk c+1 (32 back-to-back 1KB gll)
            if (c + 1 < nch) GLL_CHUNK(gbase, c + 1, bufn)
            __builtin_amdgcn_sched_barrier(0);

            // 2. compute chunk c from R
            if (c < nwarmCh) {
#pragma unroll
                for (int j = 0; j < 32; ++j) {
                    float4 iv = R[j];
                    WARM_STEP(iv.x) WARM_STEP(iv.y) WARM_STEP(iv.z) WARM_STEP(iv.w)
                }
            } else {
                // spikes overwrite bufc (input consumed into R; same-wave
                // in-order LDS), swizzled slots (j+lane)&31
#pragma unroll
                for (int j = 0; j < 32; ++j) {
                    float4 iv = R[j];
                    float4 sv;
                    FULL_STEP(iv.x, sv.x) FULL_STEP(iv.y, sv.y)
                    FULL_STEP(iv.z, sv.z) FULL_STEP(iv.w, sv.w)
                    *(float4*)&bufc[lane * LROW + (((j + lane) & 31) << 2)] = sv;
                }
                // 3. coalesced nt spike stores, two 16-reg batches
                float* og = out + (size_t)rowBase * L_DIM + t0 +
                            (size_t)(c - nwarmCh) * CHUNK;
                {
                    f32x4 S0[16];
#pragma unroll
                    for (int p = 0; p < 16; ++p)
                        S0[p] = *(const f32x4*)&bufc[p * 256 + lane * 4];
#pragma unroll
                    for (int p = 0; p < 16; ++p) {
                        const int r = 2 * p + srow;
                        __builtin_nontemporal_store(
                            S0[p], (f32x4*)(og + (size_t)r * L_DIM + (((scol - r) & 31) << 2)));
                    }
                }
                {
                    f32x4 S1[16];
#pragma unroll
                    for (int p = 0; p < 16; ++p)
                        S1[p] = *(const f32x4*)&bufc[(p + 16) * 256 + lane * 4];
#pragma unroll
                    for (int p = 0; p < 16; ++p) {
                        const int r = 2 * (p + 16) + srow;
                        __builtin_nontemporal_store(
                            S1[p], (f32x4*)(og + (size_t)r * L_DIM + (((scol - r) & 31) << 2)));
                    }
                }
            }

            // 4. counted drain + next-chunk register load
            if (c + 1 < nch) {
                if (c >= nwarmCh) {
                    // retain this iter's 32 stores; drain the 32 gll + older
                    asm volatile("s_waitcnt vmcnt(32)" ::: "memory");
                } else {
                    asm volatile("s_waitcnt vmcnt(0)" ::: "memory");
                }
                __builtin_amdgcn_sched_barrier(0);
                READ_R(bufn)
            }
        }

        // per-segment partials (exact integers < 2^24 -> float atomics exact)
        if (cnt > 0.f) {
            const int firstLocal = (int)((float)SEGLEN - accF);
            atomicMin(&firstAcc[row], t0 + firstLocal);
        }
        atomicAdd(&Cacc[row], cnt);
        atomicAdd(&tsAcc[row], fmaf((float)(t0 + SEGLEN), cnt, -accS));
    }
#undef GLL_CHUNK
#undef READ_R
}

__global__ __launch_bounds__(256) void fin_kernel(const float* __restrict__ Cacc,
                                                  const float* __restrict__ tsAcc,
                                                  const int* __restrict__ firstAcc,
                                                  float* __restrict__ out) {
    int r = blockIdx.x * 256 + threadIdx.x;
    if (r < B_DIM) {
        // firstAcc initialized to 0x7F7F7F7F by memset; clamp restores the
        // exact no-spike identity L_DIM.
        int f = firstAcc[r];
        out[(size_t)B_DIM * L_DIM + r] = (float)(f > L_DIM ? L_DIM : f);
        out[(size_t)B_DIM * L_DIM + B_DIM + r] = tsAcc[r] / (Cacc[r] + 1e-6f);
    }
}

extern "C" void kernel_launch(void* const* d_in, const int* in_sizes, int n_in,
                              void* d_out, int out_size, void* d_ws, size_t ws_size,
                              hipStream_t stream) {
    const float* I = (const float*)d_in[0];
    float* out = (float*)d_out;
    float* wsf = (float*)d_ws;
    int* wsi = (int*)((float*)d_ws + 2 * B_DIM);
    (void)in_sizes; (void)n_in; (void)out_size; (void)ws_size;

    // init via graph-capturable memsets:
    // Cacc/tsAcc = 0.0f; firstAcc = 0x7F7F7F7F (min-identity, clamped in fin)
    (void)hipMemsetAsync(wsf, 0, 2 * B_DIM * sizeof(float), stream);
    (void)hipMemsetAsync(wsi, 0x7F, B_DIM * sizeof(int), stream);
    lif_kernel<<<256, 128, 0, stream>>>(I, out, wsf, wsf + B_DIM, wsi);
    fin_kernel<<<(B_DIM + 255) / 256, 256, 0, stream>>>(wsf, wsf + B_DIM, wsi, out);
}